// Round 11
// baseline (512.662 us; speedup 1.0000x reference)
//
#include <hip/hip_runtime.h>

#define B_   4096
#define C_   8
#define G_   978
#define D0_  512
#define D1_  256
#define D2_  128
#define K_   512
#define KP_  1024          // padded G (K of enc GEMM)
#define CD_  4096          // C_*D0_

typedef short short8 __attribute__((ext_vector_type(8)));
typedef float f32x4  __attribute__((ext_vector_type(4)));

// ---------------- bf16 helpers (RNE) ----------------
__device__ __forceinline__ unsigned short f2bf(float v) {
    union { float f; unsigned u; } x; x.f = v;
    unsigned r = (x.u + 0x7fffu + ((x.u >> 16) & 1u)) >> 16;
    return (unsigned short)r;
}
__device__ __forceinline__ float bf2f(unsigned short b) {
    union { unsigned u; float f; } x; x.u = ((unsigned)b) << 16;
    return x.f;
}
// packed RNE f32x2 -> bf16x2 (lo16 = a, hi16 = b); HW RNE == f2bf bitwise
__device__ __forceinline__ unsigned cvtpk(float a, float b) {
    unsigned r;
    asm("v_cvt_pk_bf16_f32 %0, %1, %2" : "=v"(r) : "v"(a), "v"(b));
    return r;
}
__device__ __forceinline__ float ubits(unsigned u) {
    union { unsigned u; float f; } x; x.u = u;
    return x.f;
}

__device__ __forceinline__ void gload16(const unsigned short* g, unsigned short* l) {
    typedef const __attribute__((address_space(1))) unsigned int* gp_t;
    typedef __attribute__((address_space(3))) unsigned int* lp_t;
    __builtin_amdgcn_global_load_lds((gp_t)(const void*)g, (lp_t)(void*)l, 16, 0, 0);
}

// XCD-aware bijective remap (valid when nwg % 8 == 0)
__device__ __forceinline__ void xcd_remap(int& bx, int& by, int& z) {
    const int gx = gridDim.x, gy = gridDim.y;
    const int nwg = gx * gy * gridDim.z;
    int lin = blockIdx.x + gx * (blockIdx.y + gy * blockIdx.z);
    int logical = (nwg & 7) ? lin : ((lin & 7) * (nwg >> 3) + (lin >> 3));
    bx = logical % gx;
    by = (logical / gx) % gy;
    z  = logical / (gx * gy);
}

// ---------------------------------------------------------------------------
// Split-bf16 fused MFMA GEMM: C = [tanh]((Ahi+Alo)@(Bhi+Blo)^T + bias)
// Tile 128x128, BK=64, 4 waves, single-buffered 64KB LDS, 2 barriers/K-step,
// chunk-XOR swizzle (row&7) both sides.
// A_MODE 0: A via gload_lds in serial region (pre-split input).
// A_MODE 1: A raw fp32 -> reg-stage + cvt_pk split, loads fly under MFMA.
// A_MODE 2: A pre-split bf16 -> reg-stage (uint4), loads fly under MFMA.
// Serial region order: stageB FIRST (B gloads fly under A ds_writes/cvt).
// R9 lesson: do NOT reg-stage B too (VGPR spill).
// ---------------------------------------------------------------------------
template<int DO_TANH, int OUT_SPLIT, int A_MODE>
__global__ __launch_bounds__(256, 2) void mfma_split(
    const unsigned short* __restrict__ Ahi, const unsigned short* __restrict__ Alo,
    const float* __restrict__ Af, int lda, int aGrp,
    const unsigned short* __restrict__ Bhi, const unsigned short* __restrict__ Blo,
    int ldb, int bGrp,
    const float* __restrict__ bias, int biasGrp,
    float* __restrict__ Cf, unsigned short* __restrict__ Chi, unsigned short* __restrict__ Clo,
    int ldc, long long cGrp,
    int N, int kLen, int kValid, int kSplit)
{
    __shared__ __align__(16) unsigned short AsH[128 * 64];
    __shared__ __align__(16) unsigned short AsL[128 * 64];
    __shared__ __align__(16) unsigned short BsH[128 * 64];
    __shared__ __align__(16) unsigned short BsL[128 * 64];

    int bx, by, z;
    xcd_remap(bx, by, z);

    const int g = kSplit ? 0 : z;
    const int kStart = kSplit ? z * kLen : 0;
    const size_t aOff = (size_t)g * aGrp;
    const size_t bOff = (size_t)g * bGrp;
    const size_t cOff = (size_t)z * cGrp;
    const int bias0 = g * biasGrp;

    const int t = threadIdx.x;
    const int rh = t >> 3;          // 0..31: row within 32-row staging stripe
    const int ch = t & 7;           // 16B chunk within 64-elem row
    const int chs = ch ^ (rh & 7);  // pre-swizzled source chunk (gload path)
    const int rowBase = by * 128;
    const int colBase = bx * 128;

    const int wv = t >> 6, wm = wv >> 1, wn = wv & 1;
    const int l = t & 63, lr = l & 15, lk = l >> 4;
    const int xr = lr & 7;          // read-side XOR key

    f32x4 acc[4][4] = {};
    float areg[4][8];               // A_MODE 1 in-flight regs
    uint4 aH4[4], aL4[4];           // A_MODE 2 in-flight regs

    auto loadA = [&](int k0) {      // A_MODE 1: fp32, bound-checked vs kValid
        const int kbase = kStart + k0 + ch * 8;
        #pragma unroll
        for (int it = 0; it < 4; ++it) {
            const float* src = Af + aOff + (size_t)(rowBase + rh + 32 * it) * lda + kbase;
            if (kbase + 7 < kValid) {
                float2 p0 = *(const float2*)&src[0];
                float2 p1 = *(const float2*)&src[2];
                float2 p2 = *(const float2*)&src[4];
                float2 p3 = *(const float2*)&src[6];
                areg[it][0] = p0.x; areg[it][1] = p0.y;
                areg[it][2] = p1.x; areg[it][3] = p1.y;
                areg[it][4] = p2.x; areg[it][5] = p2.y;
                areg[it][6] = p3.x; areg[it][7] = p3.y;
            } else {
                #pragma unroll
                for (int j = 0; j < 8; ++j)
                    areg[it][j] = (kbase + j < kValid) ? src[j] : 0.f;
            }
        }
    };

    // cvt_pk split: hi = RNE bf16 (== f2bf); lo = RNE(v - hi), Sterbenz-exact
    auto writeA = [&]() {
        #pragma unroll
        for (int it = 0; it < 4; ++it) {
            int row = rh + 32 * it;
            unsigned hp[4], lp[4];
            #pragma unroll
            for (int p = 0; p < 4; ++p) {
                float v0 = areg[it][2 * p], v1 = areg[it][2 * p + 1];
                unsigned h = cvtpk(v0, v1);
                float h0 = ubits(h << 16);
                float h1 = ubits(h & 0xffff0000u);
                lp[p] = cvtpk(v0 - h0, v1 - h1);
                hp[p] = h;
            }
            int woff = row * 64 + (ch ^ (row & 7)) * 8;
            *(uint4*)&AsH[woff] = make_uint4(hp[0], hp[1], hp[2], hp[3]);
            *(uint4*)&AsL[woff] = make_uint4(lp[0], lp[1], lp[2], lp[3]);
        }
    };

    auto loadA2 = [&](int k0) {     // A_MODE 2: pre-split bf16, linear chunk
        const int kbase = kStart + k0 + ch * 8;
        #pragma unroll
        for (int it = 0; it < 4; ++it) {
            size_t ao = aOff + (size_t)(rowBase + rh + 32 * it) * lda + kbase;
            aH4[it] = *(const uint4*)&Ahi[ao];
            aL4[it] = *(const uint4*)&Alo[ao];
        }
    };

    auto writeA2 = [&]() {
        #pragma unroll
        for (int it = 0; it < 4; ++it) {
            int row = rh + 32 * it;
            int woff = row * 64 + (ch ^ (row & 7)) * 8;
            *(uint4*)&AsH[woff] = aH4[it];
            *(uint4*)&AsL[woff] = aL4[it];
        }
    };

    auto stageA_lds = [&](int k0) {
        const size_t kk = (size_t)(kStart + k0 + chs * 8);
        #pragma unroll
        for (int it = 0; it < 4; ++it) {
            size_t ao = aOff + (size_t)(rowBase + rh + 32 * it) * lda + kk;
            int dst = (rh + 32 * it) * 64 + ch * 8;
            gload16(Ahi + ao, &AsH[dst]);
            gload16(Alo + ao, &AsL[dst]);
        }
    };

    auto stageB = [&](int k0) {
        const size_t kk = (size_t)(kStart + k0 + chs * 8);
        #pragma unroll
        for (int it = 0; it < 4; ++it) {
            int bn = colBase + rh + 32 * it; bn = bn < N ? bn : N - 1;
            size_t bo = bOff + (size_t)bn * ldb + kk;
            int dst = (rh + 32 * it) * 64 + ch * 8;
            gload16(Bhi + bo, &BsH[dst]);
            gload16(Blo + bo, &BsL[dst]);
        }
    };

    if (A_MODE == 1) { loadA(0); stageB(0); writeA(); }
    if (A_MODE == 2) { loadA2(0); stageB(0); writeA2(); }

    for (int k0 = 0; k0 < kLen; k0 += 64) {
        if (A_MODE == 0) { stageA_lds(k0); stageB(k0); }
        __syncthreads();                       // barrier1: tile ready
        if (A_MODE == 1 && k0 + 64 < kLen) loadA(k0 + 64);    // fly under MFMA
        if (A_MODE == 2 && k0 + 64 < kLen) loadA2(k0 + 64);   // fly under MFMA
        #pragma unroll
        for (int s = 0; s < 2; ++s) {
            const int c = s * 4 + lk;
            const int co = (c ^ xr) * 8;
            short8 aH[4], aL[4], bH[4], bL[4];
            #pragma unroll
            for (int i = 0; i < 4; ++i) {
                int off = (wm * 64 + i * 16 + lr) * 64 + co;
                aH[i] = *(const short8*)&AsH[off];
                aL[i] = *(const short8*)&AsL[off];
            }
            #pragma unroll
            for (int j = 0; j < 4; ++j) {
                int off = (wn * 64 + j * 16 + lr) * 64 + co;
                bH[j] = *(const short8*)&BsH[off];
                bL[j] = *(const short8*)&BsL[off];
            }
            #pragma unroll
            for (int i = 0; i < 4; ++i)
                #pragma unroll
                for (int j = 0; j < 4; ++j) {
                    acc[i][j] = __builtin_amdgcn_mfma_f32_16x16x32_bf16(aH[i], bH[j], acc[i][j], 0, 0, 0);
                    acc[i][j] = __builtin_amdgcn_mfma_f32_16x16x32_bf16(aH[i], bL[j], acc[i][j], 0, 0, 0);
                    acc[i][j] = __builtin_amdgcn_mfma_f32_16x16x32_bf16(aL[i], bH[j], acc[i][j], 0, 0, 0);
                }
        }
        __syncthreads();                       // barrier2: reads done (drains reg loads)
        if (A_MODE == 1 && k0 + 64 < kLen) { stageB(k0 + 64); writeA(); }
        if (A_MODE == 2 && k0 + 64 < kLen) { stageB(k0 + 64); writeA2(); }
    }

    #pragma unroll
    for (int i = 0; i < 4; ++i)
        #pragma unroll
        for (int j = 0; j < 4; ++j)
            #pragma unroll
            for (int r = 0; r < 4; ++r) {
                int row = rowBase + wm * 64 + i * 16 + lk * 4 + r;
                int col = colBase + wn * 64 + j * 16 + lr;
                if (col < N) {
                    float v = acc[i][j][r];
                    if (bias) v += bias[bias0 + col];
                    if (DO_TANH) v = tanhf(v);
                    size_t off = cOff + (size_t)row * ldc + col;
                    if (OUT_SPLIT) {
                        unsigned short hh = f2bf(v);
                        Chi[off] = hh;
                        Clo[off] = f2bf(v - bf2f(hh));
                    } else {
                        Cf[off] = v;
                    }
                }
            }
}

// ---------------------------------------------------------------------------
// Pure-bf16 MFMA GEMM (decoder path): C = [tanh](A @ B^T + bias)
// ROUND-7 EXACT: tile 128x128, BK=64, 256 thr, double-buffered 64KB LDS,
// prefetch overlap, (row&7) chunk-XOR swizzle.
// ---------------------------------------------------------------------------
template<int DO_TANH, int OUT_BF>
__global__ __launch_bounds__(256, 2) void mfma_bf(
    const unsigned short* __restrict__ A, int lda, int aGrpK,
    const unsigned short* __restrict__ Bm, int ldb, long long bGrp,
    const float* __restrict__ bias, int biasGrp,
    float* __restrict__ Cf, unsigned short* __restrict__ Cbf,
    int ldc, long long cGrp,
    int N, int kLen)
{
    __shared__ __align__(16) unsigned short As[2][128 * 64];
    __shared__ __align__(16) unsigned short Bs[2][128 * 64];

    int bx, by, z;
    xcd_remap(bx, by, z);

    const size_t aOff = (size_t)z * aGrpK;
    const size_t bOff = (size_t)z * bGrp;
    const size_t cOff = (size_t)z * cGrp;
    const int bias0 = z * biasGrp;

    const int t = threadIdx.x;
    const int rh = t >> 3;          // 0..31
    const int ch = t & 7;
    const int chs = ch ^ (rh & 7);
    const int rowBase = by * 128;
    const int colBase = bx * 128;

    const int wv = t >> 6, wm = wv >> 1, wn = wv & 1;
    const int l = t & 63, lr = l & 15, lk = l >> 4;
    const int xr = lr & 7;

    f32x4 acc[4][4] = {};
    const int nsteps = kLen >> 6;

    auto stage = [&](int buf, int kAbs) {
        const size_t kk = (size_t)(kAbs + chs * 8);
        #pragma unroll
        for (int it = 0; it < 4; ++it) {
            int ar = rowBase + rh + 32 * it;
            gload16(A + aOff + (size_t)ar * lda + kk, &As[buf][(rh + 32 * it) * 64 + ch * 8]);
            int bn = colBase + rh + 32 * it; bn = bn < N ? bn : N - 1;
            gload16(Bm + bOff + (size_t)bn * ldb + kk, &Bs[buf][(rh + 32 * it) * 64 + ch * 8]);
        }
    };

    stage(0, 0);

    for (int s = 0; s < nsteps; ++s) {
        const int cur = s & 1;
        __syncthreads();
        if (s + 1 < nsteps) stage(cur ^ 1, (s + 1) * 64);
        #pragma unroll
        for (int hh = 0; hh < 2; ++hh) {
            const int co = ((hh * 4 + lk) ^ xr) * 8;
            short8 af[4], bf[4];
            #pragma unroll
            for (int i = 0; i < 4; ++i)
                af[i] = *(const short8*)&As[cur][(wm * 64 + i * 16 + lr) * 64 + co];
            #pragma unroll
            for (int j = 0; j < 4; ++j)
                bf[j] = *(const short8*)&Bs[cur][(wn * 64 + j * 16 + lr) * 64 + co];
            #pragma unroll
            for (int i = 0; i < 4; ++i)
                #pragma unroll
                for (int j = 0; j < 4; ++j)
                    acc[i][j] = __builtin_amdgcn_mfma_f32_16x16x32_bf16(af[i], bf[j], acc[i][j], 0, 0, 0);
        }
    }

    #pragma unroll
    for (int i = 0; i < 4; ++i)
        #pragma unroll
        for (int j = 0; j < 4; ++j)
            #pragma unroll
            for (int r = 0; r < 4; ++r) {
                int row = rowBase + wm * 64 + i * 16 + lk * 4 + r;
                int col = colBase + wn * 64 + j * 16 + lr;
                if (col < N) {
                    float v = acc[i][j][r];
                    if (bias) v += bias[bias0 + col];
                    if (DO_TANH) v = tanhf(v);
                    size_t off = cOff + (size_t)row * ldc + col;
                    if (OUT_BF) Cbf[off] = f2bf(v);
                    else        Cf[off] = v;
                }
            }
}

// ---------------------------------------------------------------------------
// weight transpose + split (+K pad): src fp32 [g][Ksrc][N] -> bf16 [g][N][Kdst]
// lo == nullptr -> hi-only (plain bf16).
// ---------------------------------------------------------------------------
__global__ void transpose_split(const float* __restrict__ src, long long sGrp,
                                unsigned short* __restrict__ hi, unsigned short* __restrict__ lo,
                                long long dGrp, int Ksrc, int Kdst, int N)
{
    __shared__ float tile[32][33];
    int g = blockIdx.z;
    int k0 = blockIdx.y * 32, n0 = blockIdx.x * 32;
    int tx = threadIdx.x & 31, ty = threadIdx.x >> 5;
    #pragma unroll
    for (int i = 0; i < 4; ++i) {
        int k = k0 + ty + 8 * i, n = n0 + tx;
        float v = 0.f;
        if (k < Ksrc && n < N) v = src[(size_t)g * sGrp + (size_t)k * N + n];
        tile[ty + 8 * i][tx] = v;
    }
    __syncthreads();
    #pragma unroll
    for (int i = 0; i < 4; ++i) {
        int n = n0 + ty + 8 * i, k = k0 + tx;
        if (n < N && k < Kdst) {
            float v = tile[tx][ty + 8 * i];
            unsigned short h = f2bf(v);
            size_t off = (size_t)g * dGrp + (size_t)n * Kdst + k;
            hi[off] = h;
            if (lo) lo[off] = f2bf(v - bf2f(h));
        }
    }
}

// combine split-K partials of K2 (8 slices): z1 = tanh(sum P[z] + b1)
__global__ void combine8_tanh(const float* __restrict__ P, const float* __restrict__ b1,
                              float* __restrict__ z1)
{
    const int MN = B_ * D1_;
    int i = (blockIdx.x * 256 + threadIdx.x) * 4;
    float4 s = *(const float4*)&P[i];
    #pragma unroll
    for (int j = 1; j < 8; ++j) {
        float4 p = *(const float4*)&P[i + j * MN];
        s.x += p.x; s.y += p.y; s.z += p.z; s.w += p.w;
    }
    float4 bb = *(const float4*)&b1[i & (D1_ - 1)];
    float4 o;
    o.x = tanhf(s.x + bb.x);
    o.y = tanhf(s.y + bb.y);
    o.z = tanhf(s.z + bb.z);
    o.w = tanhf(s.w + bb.w);
    *(float4*)&z1[i] = o;
}

// ---------------------------------------------------------------------------
// fp32 vector GEMM for the tiny GEMMs K3/K5; optional bf16 out (Shi).
// ---------------------------------------------------------------------------
__global__ __launch_bounds__(256) void gemm_bt(
    const float* __restrict__ A, int aRow, int aGrp,
    const float* __restrict__ Bm, int bGrp,
    const float* __restrict__ bias, int biasGrp,
    float* __restrict__ C, int cRow, int cGrp,
    int M, int N, int K, int doTanh,
    unsigned short* __restrict__ Shi)
{
    __shared__ float As[16][68];
    __shared__ float Bs[16][64];

    const int g = blockIdx.z;
    const float* Ag = A  + (size_t)g * aGrp;
    const float* Bg = Bm + (size_t)g * bGrp;
    const float* bg = bias + (size_t)g * biasGrp;

    const int tid = threadIdx.x;
    const int tx = tid & 15, ty = tid >> 4;
    const int rowBase = blockIdx.y * 64;
    const int colBase = blockIdx.x * 64;

    float acc[4][4] = {};

    for (int k0 = 0; k0 < K; k0 += 16) {
        #pragma unroll
        for (int i = 0; i < 4; ++i) {
            int e = tid + 256 * i;
            int r = e >> 4, kk = e & 15;
            int kg = k0 + kk;
            float v = 0.f;
            if (kg < K) v = Ag[(size_t)(rowBase + r) * aRow + kg];
            As[kk][r] = v;
        }
        #pragma unroll
        for (int i = 0; i < 4; ++i) {
            int e = tid + 256 * i;
            int kk = e >> 6, c = e & 63;
            int kg = k0 + kk, cg = colBase + c;
            float v = 0.f;
            if (kg < K && cg < N) v = Bg[(size_t)kg * N + cg];
            Bs[kk][c] = v;
        }
        __syncthreads();
        #pragma unroll
        for (int kk = 0; kk < 16; ++kk) {
            float4 a4 = *(const float4*)&As[kk][ty * 4];
            float4 b4 = *(const float4*)&Bs[kk][tx * 4];
            float av[4] = {a4.x, a4.y, a4.z, a4.w};
            float bv[4] = {b4.x, b4.y, b4.z, b4.w};
            #pragma unroll
            for (int i = 0; i < 4; ++i)
                #pragma unroll
                for (int j = 0; j < 4; ++j)
                    acc[i][j] = fmaf(av[i], bv[j], acc[i][j]);
        }
        __syncthreads();
    }

    #pragma unroll
    for (int i = 0; i < 4; ++i) {
        int row = rowBase + ty * 4 + i;
        #pragma unroll
        for (int j = 0; j < 4; ++j) {
            int col = colBase + tx * 4 + j;
            if (col < N) {
                float v = acc[i][j] + bg[col];
                if (doTanh) v = tanhf(v);
                size_t off = (size_t)g * cGrp + (size_t)row * cRow + col;
                if (Shi) Shi[off] = f2bf(v);
                else     C[off] = v;
            }
        }
    }
}

// ---------------- VQ ----------------
__global__ void vq_prep(const float* __restrict__ cb, double* __restrict__ csq,
                        float* __restrict__ csqf, double* __restrict__ acc)
{
    int i = threadIdx.x;
    double s = 0.0;
    for (int d = 0; d < D2_; ++d) {
        double v = (double)cb[i * D2_ + d];
        s = fma(v, v, s);
    }
    csq[i] = s;
    csqf[i] = (float)s;
    if (i == 0) *acc = 0.0;
}

// 8 rows/block, shuffle-based row-min (fmin is order-invariant -> bestv
// identical); f32 prescore + f64 re-score of margin candidates; argmin
// semantics identical to all-f64 with first-index tie-break.
__global__ __launch_bounds__(256) void vq_kernel(
    const float* __restrict__ z, const float* __restrict__ cb,
    const double* __restrict__ csq, const float* __restrict__ csqf,
    float* __restrict__ qst_out, float* __restrict__ q_ws,
    double* __restrict__ acc)
{
    __shared__ float  zsh[8][D2_];
    __shared__ float  wmin[4];
    __shared__ int    cand[64];
    __shared__ double dval[64];
    __shared__ int    ncand;
    __shared__ int    bestidx;
    __shared__ float  lsum[256];

    const int b0 = blockIdx.x * 8;
    const int t = threadIdx.x;
    const int wv = t >> 6, l = t & 63;

    #pragma unroll
    for (int i = 0; i < 4; ++i)
        ((float*)zsh)[t + 256 * i] = z[(size_t)b0 * D2_ + t + 256 * i];
    __syncthreads();

    float sc[2][8];
    #pragma unroll
    for (int ii = 0; ii < 2; ++ii) {
        int i = t + (ii << 8);
        const float4* cr = (const float4*)(cb + (size_t)i * D2_);
        float d[8] = {};
        #pragma unroll 2
        for (int d4 = 0; d4 < 32; ++d4) {
            float4 c4 = cr[d4];
            #pragma unroll
            for (int r = 0; r < 8; ++r) {
                float4 zr = ((const float4*)zsh[r])[d4];
                d[r] = fmaf(c4.x, zr.x, fmaf(c4.y, zr.y, fmaf(c4.z, zr.z, fmaf(c4.w, zr.w, d[r]))));
            }
        }
        float cs = csqf[i];
        #pragma unroll
        for (int r = 0; r < 8; ++r) sc[ii][r] = cs - 2.f * d[r];
    }

    float lossAcc = 0.f;
    #pragma unroll
    for (int r = 0; r < 8; ++r) {
        float m = fminf(sc[0][r], sc[1][r]);
        #pragma unroll
        for (int o = 1; o < 64; o <<= 1)
            m = fminf(m, __shfl_xor(m, o));
        if (l == 0) wmin[wv] = m;
        if (t == 0) ncand = 0;
        __syncthreads();                                      // b1
        float bestv = fminf(fminf(wmin[0], wmin[1]), fminf(wmin[2], wmin[3]));
        #pragma unroll
        for (int ii = 0; ii < 2; ++ii)
            if (sc[ii][r] <= bestv + 1e-5f) {
                int p = atomicAdd(&ncand, 1);
                if (p < 64) cand[p] = t + (ii << 8);
            }
        __syncthreads();                                      // b2
        int nc = ncand < 64 ? ncand : 64;
        if (t < nc) {
            int i = cand[t];
            const float* cr = cb + (size_t)i * D2_;
            double dot = 0.0;
            for (int d2 = 0; d2 < D2_; ++d2)
                dot = fma((double)cr[d2], (double)zsh[r][d2], dot);
            dval[t] = csq[i] - 2.0 * dot;
        }
        __syncthreads();                                      // b3
        if (t == 0) {
            double bv = 1e300; int bi = 0x7fffffff;
            for (int j2 = 0; j2 < nc; ++j2) {
                double v = dval[j2]; int i2 = cand[j2];
                if (v < bv || (v == bv && i2 < bi)) { bv = v; bi = i2; }
            }
            bestidx = bi;
        }
        __syncthreads();                                      // b4
        int idx = bestidx;
        if (t < D2_) {
            float qv = cb[(size_t)idx * D2_ + t];
            size_t o = (size_t)(b0 + r) * D2_ + t;
            qst_out[o] = qv;
            q_ws[o] = qv;
            float d = qv - zsh[r][t];
            lossAcc += d * d;
        }
        __syncthreads();                                      // b5 (protects cand/wmin reuse)
    }
    lsum[t] = lossAcc;
    __syncthreads();
    for (int off = 128; off > 0; off >>= 1) {
        if (t < off) lsum[t] += lsum[t + off];
        __syncthreads();
    }
    if (t == 0) atomicAdd(acc, (double)lsum[0]);
}

__global__ void finalize_loss(const double* __restrict__ acc, float* __restrict__ out0)
{
    out0[0] = (float)(1.25 * (*acc) / (double)((size_t)B_ * D2_));
}

// ---------------------------------------------------------------------------
extern "C" void kernel_launch(void* const* d_in, const int* in_sizes, int n_in,
                              void* d_out, int out_size, void* d_ws, size_t ws_size,
                              hipStream_t stream)
{
    const float* inputs = (const float*)d_in[0];
    const float* enc_w  = (const float*)d_in[1];
    const float* enc_b  = (const float*)d_in[2];
    const float* w1     = (const float*)d_in[3];
    const float* b1     = (const float*)d_in[4];
    const float* w2     = (const float*)d_in[5];
    const float* b2     = (const float*)d_in[6];
    const float* cb     = (const float*)d_in[7];
    const float* dw1    = (const float*)d_in[8];
    const float* db1    = (const float*)d_in[9];
    const float* dw2    = (const float*)d_in[10];
    const float* db2    = (const float*)d_in[11];
    const float* dec_w  = (const float*)d_in[12];
    const float* dec_b  = (const float*)d_in[13];

    float* out = (float*)d_out;
    float* x_recon = out + 1;
    float* qst     = out + 1 + (size_t)B_ * C_ * G_;

    const size_t MB = 1u << 20;
    const size_t NEED = 172 * MB;
    dim3 blk(256);

    if (ws_size >= NEED) {
        char* W = (char*)d_ws;
        unsigned short* ewt_hi = (unsigned short*)(W + 0);         // 8MB
        unsigned short* ewt_lo = (unsigned short*)(W + 8 * MB);    // 8MB
        unsigned short* h_hi   = (unsigned short*)(W + 16 * MB);   // 32MB
        unsigned short* h_lo   = (unsigned short*)(W + 48 * MB);   // 32MB
        unsigned short* w1t_hi = (unsigned short*)(W + 80 * MB);   // 2MB
        unsigned short* w1t_lo = (unsigned short*)(W + 82 * MB);   // 2MB
        unsigned short* dw2t   = (unsigned short*)(W + 84 * MB);   // 2MB (bf16 only)
        unsigned short* dwt    = (unsigned short*)(W + 86 * MB);   // 7.65MB (bf16 only)
        float* partials = (float*)(W + 94 * MB);                   // 32MB (8 slices)
        float* z1 = (float*)(W + 126 * MB);                        // 4MB
        float* z  = (float*)(W + 130 * MB);                        // 2MB
        float* q  = (float*)(W + 132 * MB);                        // 2MB
        unsigned short* r1_bf = (unsigned short*)(W + 134 * MB);   // 2MB
        unsigned short* r_bf  = (unsigned short*)(W + 136 * MB);   // 32MB -> ends 168MB
        double* csq  = (double*)(W + 168 * MB);                    // 4KB
        double* acc  = (double*)(W + 168 * MB + 4096);
        float*  csqf = (float*)(W + 168 * MB + 4096 + 64);

        // weight prep (inputs are split on the fly in K1)
        transpose_split<<<dim3(16, 32, 8), blk, 0, stream>>>(
            enc_w, (long long)G_ * D0_, ewt_hi, ewt_lo, (long long)D0_ * KP_, G_, KP_, D0_);
        transpose_split<<<dim3(8, 128, 1), blk, 0, stream>>>(
            w1, 0, w1t_hi, w1t_lo, 0, CD_, CD_, D1_);
        transpose_split<<<dim3(128, 8, 1), blk, 0, stream>>>(
            dw2, 0, dw2t, nullptr, 0, D1_, D1_, CD_);
        transpose_split<<<dim3(31, 16, 8), blk, 0, stream>>>(
            dec_w, (long long)D0_ * G_, dwt, nullptr, (long long)G_ * D0_, D0_, D0_, G_);

        // K1: h = tanh(inputs @ enc_w + enc_b); A = raw fp32, split on the fly
        mfma_split<1, 1, 1><<<dim3(4, 32, 8), blk, 0, stream>>>(
            nullptr, nullptr, inputs, C_ * G_, G_,
            ewt_hi, ewt_lo, KP_, D0_ * KP_,
            enc_b, D0_,
            nullptr, h_hi, h_lo, CD_, 512LL,
            D0_, KP_, G_, 0);

        // K2: partials[z] = h @ w1 (split-K = 8), reg-staged A overlap
        mfma_split<0, 0, 2><<<dim3(2, 32, 8), blk, 0, stream>>>(
            h_hi, h_lo, nullptr, CD_, 0,
            w1t_hi, w1t_lo, CD_, 0,
            nullptr, 0,
            partials, nullptr, nullptr, D1_, (long long)B_ * D1_,
            D1_, CD_ / 8, CD_ / 8, 1);
        combine8_tanh<<<dim3(B_ * D1_ / 1024), blk, 0, stream>>>(partials, b1, z1);

        // K3: z = tanh(z1 @ w2 + b2)  (fp32)
        gemm_bt<<<dim3(2, 64, 1), blk, 0, stream>>>(
            z1, D1_, 0, w2, 0, b2, 0, z, D2_, 0, B_, D2_, D1_, 1, nullptr);

        // VQ
        vq_prep<<<dim3(1), dim3(K_), 0, stream>>>(cb, csq, csqf, acc);
        vq_kernel<<<dim3(B_ / 8), blk, 0, stream>>>(z, cb, csq, csqf, qst, q, acc);

        // K5: r1 = tanh(q @ dw1 + db1)  (fp32 compute, bf16 out)
        gemm_bt<<<dim3(4, 64, 1), blk, 0, stream>>>(
            q, D2_, 0, dw1, 0, db1, 0, nullptr, D1_, 0, B_, D1_, D2_, 1, r1_bf);

        // K6: r = tanh(r1 @ dw2 + db2), pure bf16
        mfma_bf<1, 1><<<dim3(32, 32, 1), blk, 0, stream>>>(
            r1_bf, D1_, 0,
            dw2t, D1_, 0,
            db2, 0,
            nullptr, r_bf, CD_, 0LL,
            CD_, D1_);

        // K7: x_recon = r @ dec_w + dec_b (grouped, pure bf16, fp32 out)
        mfma_bf<0, 0><<<dim3(8, 32, 8), blk, 0, stream>>>(
            r_bf, CD_, 512,
            dwt, D0_, (long long)G_ * D0_,
            dec_b, G_,
            x_recon, nullptr, C_ * G_, (long long)G_,
            G_, D0_);

        finalize_loss<<<dim3(1), dim3(1), 0, stream>>>(acc, out);
    } else {
        // -------- fallback: fp32 path --------
        float*  h   = (float*)d_ws;
        float*  z1  = h  + (size_t)B_ * CD_;
        float*  z   = z1 + (size_t)B_ * D1_;
        float*  q   = z  + (size_t)B_ * D2_;
        double* csq = (double*)(q + (size_t)B_ * D2_);
        double* acc = csq + K_;
        float*  csqf = (float*)(acc + 8);

        gemm_bt<<<dim3(D0_ / 64, B_ / 64, C_), blk, 0, stream>>>(
            inputs, C_ * G_, G_, enc_w, G_ * D0_, enc_b, D0_,
            h, CD_, D0_, B_, D0_, G_, 1, nullptr);
        gemm_bt<<<dim3(D1_ / 64, B_ / 64, 1), blk, 0, stream>>>(
            h, CD_, 0, w1, 0, b1, 0, z1, D1_, 0, B_, D1_, CD_, 1, nullptr);
        gemm_bt<<<dim3(D2_ / 64, B_ / 64, 1), blk, 0, stream>>>(
            z1, D1_, 0, w2, 0, b2, 0, z, D2_, 0, B_, D2_, D1_, 1, nullptr);
        vq_prep<<<dim3(1), dim3(K_), 0, stream>>>(cb, csq, csqf, acc);
        vq_kernel<<<dim3(B_ / 8), blk, 0, stream>>>(z, cb, csq, csqf, qst, q, acc);
        gemm_bt<<<dim3(D1_ / 64, B_ / 64, 1), blk, 0, stream>>>(
            q, D2_, 0, dw1, 0, db1, 0, z1, D1_, 0, B_, D1_, D2_, 1, nullptr);
        gemm_bt<<<dim3(CD_ / 64, B_ / 64, 1), blk, 0, stream>>>(
            z1, D1_, 0, dw2, 0, db2, 0, h, CD_, 0, B_, CD_, D1_, 1, nullptr);
        gemm_bt<<<dim3((G_ + 63) / 64, B_ / 64, C_), blk, 0, stream>>>(
            h, CD_, D0_, dec_w, D0_ * G_, dec_b, G_,
            x_recon, C_ * G_, G_, B_, G_, D0_, 0, nullptr);
        finalize_loss<<<dim3(1), dim3(1), 0, stream>>>(acc, out);
    }
}

// Round 12
// 461.529 us; speedup vs baseline: 1.1108x; 1.1108x over previous
//
#include <hip/hip_runtime.h>

#define B_   4096
#define C_   8
#define G_   978
#define D0_  512
#define D1_  256
#define D2_  128
#define K_   512
#define KP_  1024          // padded G (K of enc GEMM)
#define CD_  4096          // C_*D0_

typedef short short8 __attribute__((ext_vector_type(8)));
typedef float f32x4  __attribute__((ext_vector_type(4)));

// ---------------- bf16 helpers (RNE) ----------------
__device__ __forceinline__ unsigned short f2bf(float v) {
    union { float f; unsigned u; } x; x.f = v;
    unsigned r = (x.u + 0x7fffu + ((x.u >> 16) & 1u)) >> 16;
    return (unsigned short)r;
}
__device__ __forceinline__ float bf2f(unsigned short b) {
    union { unsigned u; float f; } x; x.u = ((unsigned)b) << 16;
    return x.f;
}
// packed RNE f32x2 -> bf16x2 (lo16 = a, hi16 = b); HW RNE == f2bf bitwise
__device__ __forceinline__ unsigned cvtpk(float a, float b) {
    unsigned r;
    asm("v_cvt_pk_bf16_f32 %0, %1, %2" : "=v"(r) : "v"(a), "v"(b));
    return r;
}
__device__ __forceinline__ float ubits(unsigned u) {
    union { unsigned u; float f; } x; x.u = u;
    return x.f;
}

__device__ __forceinline__ void gload16(const unsigned short* g, unsigned short* l) {
    typedef const __attribute__((address_space(1))) unsigned int* gp_t;
    typedef __attribute__((address_space(3))) unsigned int* lp_t;
    __builtin_amdgcn_global_load_lds((gp_t)(const void*)g, (lp_t)(void*)l, 16, 0, 0);
}

// XCD-aware bijective remap (valid when nwg % 8 == 0)
__device__ __forceinline__ void xcd_remap(int& bx, int& by, int& z) {
    const int gx = gridDim.x, gy = gridDim.y;
    const int nwg = gx * gy * gridDim.z;
    int lin = blockIdx.x + gx * (blockIdx.y + gy * blockIdx.z);
    int logical = (nwg & 7) ? lin : ((lin & 7) * (nwg >> 3) + (lin >> 3));
    bx = logical % gx;
    by = (logical / gx) % gy;
    z  = logical / (gx * gy);
}

// ---------------------------------------------------------------------------
// Split-bf16 fused MFMA GEMM: C = [tanh]((Ahi+Alo)@(Bhi+Blo)^T + bias)
// ROUND-7/10 PROVEN VERSION (165us K1, 0 conflicts, no spills): tile 128x128,
// BK=64, 4 waves, single-buffered 64KB LDS, 2 barriers/K-step, chunk-XOR
// swizzle (row&7) both sides. A_F32: A fp32 reg-staged + cvt_pk hi/lo split;
// next A-tile loads issued after barrier1 (fly under MFMA); serial region =
// writeA THEN stageB (R11 lesson: issuing stageB first regresses — the gload
// LDS-writes contend with writeA's ds_writes). R9 lesson: do NOT reg-stage B
// (VGPR spill).
// ---------------------------------------------------------------------------
template<int DO_TANH, int OUT_SPLIT, int A_F32>
__global__ __launch_bounds__(256, 2) void mfma_split(
    const unsigned short* __restrict__ Ahi, const unsigned short* __restrict__ Alo,
    const float* __restrict__ Af, int lda, int aGrp,
    const unsigned short* __restrict__ Bhi, const unsigned short* __restrict__ Blo,
    int ldb, int bGrp,
    const float* __restrict__ bias, int biasGrp,
    float* __restrict__ Cf, unsigned short* __restrict__ Chi, unsigned short* __restrict__ Clo,
    int ldc, long long cGrp,
    int N, int kLen, int kValid, int kSplit)
{
    __shared__ __align__(16) unsigned short AsH[128 * 64];
    __shared__ __align__(16) unsigned short AsL[128 * 64];
    __shared__ __align__(16) unsigned short BsH[128 * 64];
    __shared__ __align__(16) unsigned short BsL[128 * 64];

    int bx, by, z;
    xcd_remap(bx, by, z);

    const int g = kSplit ? 0 : z;
    const int kStart = kSplit ? z * kLen : 0;
    const size_t aOff = (size_t)g * aGrp;
    const size_t bOff = (size_t)g * bGrp;
    const size_t cOff = (size_t)z * cGrp;
    const int bias0 = g * biasGrp;

    const int t = threadIdx.x;
    const int rh = t >> 3;          // 0..31: row within 32-row staging stripe
    const int ch = t & 7;           // 16B chunk within 64-elem row
    const int chs = ch ^ (rh & 7);  // pre-swizzled source chunk (gload path)
    const int rowBase = by * 128;
    const int colBase = bx * 128;

    const int wv = t >> 6, wm = wv >> 1, wn = wv & 1;
    const int l = t & 63, lr = l & 15, lk = l >> 4;
    const int xr = lr & 7;          // read-side XOR key

    f32x4 acc[4][4] = {};
    float areg[4][8];               // A_F32 in-flight regs (static indexing only)

    auto loadA = [&](int k0) {
        const int kbase = kStart + k0 + ch * 8;
        #pragma unroll
        for (int it = 0; it < 4; ++it) {
            const float* src = Af + aOff + (size_t)(rowBase + rh + 32 * it) * lda + kbase;
            if (kbase + 7 < kValid) {
                float2 p0 = *(const float2*)&src[0];
                float2 p1 = *(const float2*)&src[2];
                float2 p2 = *(const float2*)&src[4];
                float2 p3 = *(const float2*)&src[6];
                areg[it][0] = p0.x; areg[it][1] = p0.y;
                areg[it][2] = p1.x; areg[it][3] = p1.y;
                areg[it][4] = p2.x; areg[it][5] = p2.y;
                areg[it][6] = p3.x; areg[it][7] = p3.y;
            } else {
                #pragma unroll
                for (int j = 0; j < 8; ++j)
                    areg[it][j] = (kbase + j < kValid) ? src[j] : 0.f;
            }
        }
    };

    // cvt_pk split: hi = RNE bf16 (== f2bf); lo = RNE(v - hi), Sterbenz-exact
    auto writeA = [&]() {
        #pragma unroll
        for (int it = 0; it < 4; ++it) {
            int row = rh + 32 * it;
            unsigned hp[4], lp[4];
            #pragma unroll
            for (int p = 0; p < 4; ++p) {
                float v0 = areg[it][2 * p], v1 = areg[it][2 * p + 1];
                unsigned h = cvtpk(v0, v1);
                float h0 = ubits(h << 16);
                float h1 = ubits(h & 0xffff0000u);
                lp[p] = cvtpk(v0 - h0, v1 - h1);
                hp[p] = h;
            }
            int woff = row * 64 + (ch ^ (row & 7)) * 8;
            *(uint4*)&AsH[woff] = make_uint4(hp[0], hp[1], hp[2], hp[3]);
            *(uint4*)&AsL[woff] = make_uint4(lp[0], lp[1], lp[2], lp[3]);
        }
    };

    auto stageA_lds = [&](int k0) {
        const size_t kk = (size_t)(kStart + k0 + chs * 8);
        #pragma unroll
        for (int it = 0; it < 4; ++it) {
            size_t ao = aOff + (size_t)(rowBase + rh + 32 * it) * lda + kk;
            int dst = (rh + 32 * it) * 64 + ch * 8;
            gload16(Ahi + ao, &AsH[dst]);
            gload16(Alo + ao, &AsL[dst]);
        }
    };

    auto stageB = [&](int k0) {
        const size_t kk = (size_t)(kStart + k0 + chs * 8);
        #pragma unroll
        for (int it = 0; it < 4; ++it) {
            int bn = colBase + rh + 32 * it; bn = bn < N ? bn : N - 1;
            size_t bo = bOff + (size_t)bn * ldb + kk;
            int dst = (rh + 32 * it) * 64 + ch * 8;
            gload16(Bhi + bo, &BsH[dst]);
            gload16(Blo + bo, &BsL[dst]);
        }
    };

    if (A_F32) { loadA(0); writeA(); stageB(0); }

    for (int k0 = 0; k0 < kLen; k0 += 64) {
        if (!A_F32) { stageA_lds(k0); stageB(k0); }
        __syncthreads();                       // barrier1: tile ready
        if (A_F32 && k0 + 64 < kLen) loadA(k0 + 64);   // fly under MFMA
        #pragma unroll
        for (int s = 0; s < 2; ++s) {
            const int c = s * 4 + lk;
            const int co = (c ^ xr) * 8;
            short8 aH[4], aL[4], bH[4], bL[4];
            #pragma unroll
            for (int i = 0; i < 4; ++i) {
                int off = (wm * 64 + i * 16 + lr) * 64 + co;
                aH[i] = *(const short8*)&AsH[off];
                aL[i] = *(const short8*)&AsL[off];
            }
            #pragma unroll
            for (int j = 0; j < 4; ++j) {
                int off = (wn * 64 + j * 16 + lr) * 64 + co;
                bH[j] = *(const short8*)&BsH[off];
                bL[j] = *(const short8*)&BsL[off];
            }
            #pragma unroll
            for (int i = 0; i < 4; ++i)
                #pragma unroll
                for (int j = 0; j < 4; ++j) {
                    acc[i][j] = __builtin_amdgcn_mfma_f32_16x16x32_bf16(aH[i], bH[j], acc[i][j], 0, 0, 0);
                    acc[i][j] = __builtin_amdgcn_mfma_f32_16x16x32_bf16(aH[i], bL[j], acc[i][j], 0, 0, 0);
                    acc[i][j] = __builtin_amdgcn_mfma_f32_16x16x32_bf16(aL[i], bH[j], acc[i][j], 0, 0, 0);
                }
        }
        __syncthreads();                       // barrier2: reads done (drains loadA)
        if (A_F32 && k0 + 64 < kLen) { writeA(); stageB(k0 + 64); }
    }

    #pragma unroll
    for (int i = 0; i < 4; ++i)
        #pragma unroll
        for (int j = 0; j < 4; ++j)
            #pragma unroll
            for (int r = 0; r < 4; ++r) {
                int row = rowBase + wm * 64 + i * 16 + lk * 4 + r;
                int col = colBase + wn * 64 + j * 16 + lr;
                if (col < N) {
                    float v = acc[i][j][r];
                    if (bias) v += bias[bias0 + col];
                    if (DO_TANH) v = tanhf(v);
                    size_t off = cOff + (size_t)row * ldc + col;
                    if (OUT_SPLIT) {
                        unsigned short hh = f2bf(v);
                        Chi[off] = hh;
                        Clo[off] = f2bf(v - bf2f(hh));
                    } else {
                        Cf[off] = v;
                    }
                }
            }
}

// ---------------------------------------------------------------------------
// Pure-bf16 MFMA GEMM (decoder path): C = [tanh](A @ B^T + bias)
// ROUND-7 EXACT: tile 128x128, BK=64, 256 thr, double-buffered 64KB LDS,
// prefetch overlap, (row&7) chunk-XOR swizzle.
// ---------------------------------------------------------------------------
template<int DO_TANH, int OUT_BF>
__global__ __launch_bounds__(256, 2) void mfma_bf(
    const unsigned short* __restrict__ A, int lda, int aGrpK,
    const unsigned short* __restrict__ Bm, int ldb, long long bGrp,
    const float* __restrict__ bias, int biasGrp,
    float* __restrict__ Cf, unsigned short* __restrict__ Cbf,
    int ldc, long long cGrp,
    int N, int kLen)
{
    __shared__ __align__(16) unsigned short As[2][128 * 64];
    __shared__ __align__(16) unsigned short Bs[2][128 * 64];

    int bx, by, z;
    xcd_remap(bx, by, z);

    const size_t aOff = (size_t)z * aGrpK;
    const size_t bOff = (size_t)z * bGrp;
    const size_t cOff = (size_t)z * cGrp;
    const int bias0 = z * biasGrp;

    const int t = threadIdx.x;
    const int rh = t >> 3;          // 0..31
    const int ch = t & 7;
    const int chs = ch ^ (rh & 7);
    const int rowBase = by * 128;
    const int colBase = bx * 128;

    const int wv = t >> 6, wm = wv >> 1, wn = wv & 1;
    const int l = t & 63, lr = l & 15, lk = l >> 4;
    const int xr = lr & 7;

    f32x4 acc[4][4] = {};
    const int nsteps = kLen >> 6;

    auto stage = [&](int buf, int kAbs) {
        const size_t kk = (size_t)(kAbs + chs * 8);
        #pragma unroll
        for (int it = 0; it < 4; ++it) {
            int ar = rowBase + rh + 32 * it;
            gload16(A + aOff + (size_t)ar * lda + kk, &As[buf][(rh + 32 * it) * 64 + ch * 8]);
            int bn = colBase + rh + 32 * it; bn = bn < N ? bn : N - 1;
            gload16(Bm + bOff + (size_t)bn * ldb + kk, &Bs[buf][(rh + 32 * it) * 64 + ch * 8]);
        }
    };

    stage(0, 0);

    for (int s = 0; s < nsteps; ++s) {
        const int cur = s & 1;
        __syncthreads();
        if (s + 1 < nsteps) stage(cur ^ 1, (s + 1) * 64);
        #pragma unroll
        for (int hh = 0; hh < 2; ++hh) {
            const int co = ((hh * 4 + lk) ^ xr) * 8;
            short8 af[4], bf[4];
            #pragma unroll
            for (int i = 0; i < 4; ++i)
                af[i] = *(const short8*)&As[cur][(wm * 64 + i * 16 + lr) * 64 + co];
            #pragma unroll
            for (int j = 0; j < 4; ++j)
                bf[j] = *(const short8*)&Bs[cur][(wn * 64 + j * 16 + lr) * 64 + co];
            #pragma unroll
            for (int i = 0; i < 4; ++i)
                #pragma unroll
                for (int j = 0; j < 4; ++j)
                    acc[i][j] = __builtin_amdgcn_mfma_f32_16x16x32_bf16(af[i], bf[j], acc[i][j], 0, 0, 0);
        }
    }

    #pragma unroll
    for (int i = 0; i < 4; ++i)
        #pragma unroll
        for (int j = 0; j < 4; ++j)
            #pragma unroll
            for (int r = 0; r < 4; ++r) {
                int row = rowBase + wm * 64 + i * 16 + lk * 4 + r;
                int col = colBase + wn * 64 + j * 16 + lr;
                if (col < N) {
                    float v = acc[i][j][r];
                    if (bias) v += bias[bias0 + col];
                    if (DO_TANH) v = tanhf(v);
                    size_t off = cOff + (size_t)row * ldc + col;
                    if (OUT_BF) Cbf[off] = f2bf(v);
                    else        Cf[off] = v;
                }
            }
}

// ---------------------------------------------------------------------------
// weight transpose + split (+K pad): src fp32 [g][Ksrc][N] -> bf16 [g][N][Kdst]
// lo == nullptr -> hi-only (plain bf16).
// ---------------------------------------------------------------------------
__global__ void transpose_split(const float* __restrict__ src, long long sGrp,
                                unsigned short* __restrict__ hi, unsigned short* __restrict__ lo,
                                long long dGrp, int Ksrc, int Kdst, int N)
{
    __shared__ float tile[32][33];
    int g = blockIdx.z;
    int k0 = blockIdx.y * 32, n0 = blockIdx.x * 32;
    int tx = threadIdx.x & 31, ty = threadIdx.x >> 5;
    #pragma unroll
    for (int i = 0; i < 4; ++i) {
        int k = k0 + ty + 8 * i, n = n0 + tx;
        float v = 0.f;
        if (k < Ksrc && n < N) v = src[(size_t)g * sGrp + (size_t)k * N + n];
        tile[ty + 8 * i][tx] = v;
    }
    __syncthreads();
    #pragma unroll
    for (int i = 0; i < 4; ++i) {
        int n = n0 + ty + 8 * i, k = k0 + tx;
        if (n < N && k < Kdst) {
            float v = tile[tx][ty + 8 * i];
            unsigned short h = f2bf(v);
            size_t off = (size_t)g * dGrp + (size_t)n * Kdst + k;
            hi[off] = h;
            if (lo) lo[off] = f2bf(v - bf2f(h));
        }
    }
}

// combine split-K partials of K2 (8 slices): z1 = tanh(sum P[z] + b1)
__global__ void combine8_tanh(const float* __restrict__ P, const float* __restrict__ b1,
                              float* __restrict__ z1)
{
    const int MN = B_ * D1_;
    int i = (blockIdx.x * 256 + threadIdx.x) * 4;
    float4 s = *(const float4*)&P[i];
    #pragma unroll
    for (int j = 1; j < 8; ++j) {
        float4 p = *(const float4*)&P[i + j * MN];
        s.x += p.x; s.y += p.y; s.z += p.z; s.w += p.w;
    }
    float4 bb = *(const float4*)&b1[i & (D1_ - 1)];
    float4 o;
    o.x = tanhf(s.x + bb.x);
    o.y = tanhf(s.y + bb.y);
    o.z = tanhf(s.z + bb.z);
    o.w = tanhf(s.w + bb.w);
    *(float4*)&z1[i] = o;
}

// ---------------------------------------------------------------------------
// fp32 vector GEMM for the tiny GEMMs K3/K5; optional bf16 out (Shi).
// ---------------------------------------------------------------------------
__global__ __launch_bounds__(256) void gemm_bt(
    const float* __restrict__ A, int aRow, int aGrp,
    const float* __restrict__ Bm, int bGrp,
    const float* __restrict__ bias, int biasGrp,
    float* __restrict__ C, int cRow, int cGrp,
    int M, int N, int K, int doTanh,
    unsigned short* __restrict__ Shi)
{
    __shared__ float As[16][68];
    __shared__ float Bs[16][64];

    const int g = blockIdx.z;
    const float* Ag = A  + (size_t)g * aGrp;
    const float* Bg = Bm + (size_t)g * bGrp;
    const float* bg = bias + (size_t)g * biasGrp;

    const int tid = threadIdx.x;
    const int tx = tid & 15, ty = tid >> 4;
    const int rowBase = blockIdx.y * 64;
    const int colBase = blockIdx.x * 64;

    float acc[4][4] = {};

    for (int k0 = 0; k0 < K; k0 += 16) {
        #pragma unroll
        for (int i = 0; i < 4; ++i) {
            int e = tid + 256 * i;
            int r = e >> 4, kk = e & 15;
            int kg = k0 + kk;
            float v = 0.f;
            if (kg < K) v = Ag[(size_t)(rowBase + r) * aRow + kg];
            As[kk][r] = v;
        }
        #pragma unroll
        for (int i = 0; i < 4; ++i) {
            int e = tid + 256 * i;
            int kk = e >> 6, c = e & 63;
            int kg = k0 + kk, cg = colBase + c;
            float v = 0.f;
            if (kg < K && cg < N) v = Bg[(size_t)kg * N + cg];
            Bs[kk][c] = v;
        }
        __syncthreads();
        #pragma unroll
        for (int kk = 0; kk < 16; ++kk) {
            float4 a4 = *(const float4*)&As[kk][ty * 4];
            float4 b4 = *(const float4*)&Bs[kk][tx * 4];
            float av[4] = {a4.x, a4.y, a4.z, a4.w};
            float bv[4] = {b4.x, b4.y, b4.z, b4.w};
            #pragma unroll
            for (int i = 0; i < 4; ++i)
                #pragma unroll
                for (int j = 0; j < 4; ++j)
                    acc[i][j] = fmaf(av[i], bv[j], acc[i][j]);
        }
        __syncthreads();
    }

    #pragma unroll
    for (int i = 0; i < 4; ++i) {
        int row = rowBase + ty * 4 + i;
        #pragma unroll
        for (int j = 0; j < 4; ++j) {
            int col = colBase + tx * 4 + j;
            if (col < N) {
                float v = acc[i][j] + bg[col];
                if (doTanh) v = tanhf(v);
                size_t off = (size_t)g * cGrp + (size_t)row * cRow + col;
                if (Shi) Shi[off] = f2bf(v);
                else     C[off] = v;
            }
        }
    }
}

// ---------------- VQ ----------------
__global__ void vq_prep(const float* __restrict__ cb, double* __restrict__ csq,
                        float* __restrict__ csqf, double* __restrict__ acc)
{
    int i = threadIdx.x;
    double s = 0.0;
    for (int d = 0; d < D2_; ++d) {
        double v = (double)cb[i * D2_ + d];
        s = fma(v, v, s);
    }
    csq[i] = s;
    csqf[i] = (float)s;
    if (i == 0) *acc = 0.0;
}

// 8 rows/block (validated R9/R10): f32 prescore + f64 re-score of margin
// candidates; argmin semantics identical to all-f64 with first-index
// tie-break. LDS-tree reduce (R11's shuffle variant was part of a regression
// bundle — keep the proven tree).
__global__ __launch_bounds__(256) void vq_kernel(
    const float* __restrict__ z, const float* __restrict__ cb,
    const double* __restrict__ csq, const float* __restrict__ csqf,
    float* __restrict__ qst_out, float* __restrict__ q_ws,
    double* __restrict__ acc)
{
    __shared__ float  zsh[8][D2_];
    __shared__ float  rmin[256];
    __shared__ int    cand[64];
    __shared__ double dval[64];
    __shared__ int    ncand;
    __shared__ int    bestidx;
    __shared__ float  lsum[256];

    const int b0 = blockIdx.x * 8;
    const int t = threadIdx.x;

    #pragma unroll
    for (int i = 0; i < 4; ++i)
        ((float*)zsh)[t + 256 * i] = z[(size_t)b0 * D2_ + t + 256 * i];
    __syncthreads();

    float sc[2][8];
    #pragma unroll
    for (int ii = 0; ii < 2; ++ii) {
        int i = t + (ii << 8);
        const float4* cr = (const float4*)(cb + (size_t)i * D2_);
        float d[8] = {};
        #pragma unroll 2
        for (int d4 = 0; d4 < 32; ++d4) {
            float4 c4 = cr[d4];
            #pragma unroll
            for (int r = 0; r < 8; ++r) {
                float4 zr = ((const float4*)zsh[r])[d4];
                d[r] = fmaf(c4.x, zr.x, fmaf(c4.y, zr.y, fmaf(c4.z, zr.z, fmaf(c4.w, zr.w, d[r]))));
            }
        }
        float cs = csqf[i];
        #pragma unroll
        for (int r = 0; r < 8; ++r) sc[ii][r] = cs - 2.f * d[r];
    }

    float lossAcc = 0.f;
    #pragma unroll
    for (int r = 0; r < 8; ++r) {
        rmin[t] = fminf(sc[0][r], sc[1][r]);
        __syncthreads();
        for (int off = 128; off > 0; off >>= 1) {
            if (t < off) rmin[t] = fminf(rmin[t], rmin[t + off]);
            __syncthreads();
        }
        float bestv = rmin[0];
        if (t == 0) ncand = 0;
        __syncthreads();
        #pragma unroll
        for (int ii = 0; ii < 2; ++ii)
            if (sc[ii][r] <= bestv + 1e-5f) {
                int p = atomicAdd(&ncand, 1);
                if (p < 64) cand[p] = t + (ii << 8);
            }
        __syncthreads();
        int nc = ncand < 64 ? ncand : 64;
        if (t < nc) {
            int i = cand[t];
            const float* cr = cb + (size_t)i * D2_;
            double dot = 0.0;
            for (int d2 = 0; d2 < D2_; ++d2)
                dot = fma((double)cr[d2], (double)zsh[r][d2], dot);
            dval[t] = csq[i] - 2.0 * dot;
        }
        __syncthreads();
        if (t == 0) {
            double bv = 1e300; int bi = 0x7fffffff;
            for (int j2 = 0; j2 < nc; ++j2) {
                double v = dval[j2]; int i2 = cand[j2];
                if (v < bv || (v == bv && i2 < bi)) { bv = v; bi = i2; }
            }
            bestidx = bi;
        }
        __syncthreads();
        int idx = bestidx;
        if (t < D2_) {
            float qv = cb[(size_t)idx * D2_ + t];
            size_t o = (size_t)(b0 + r) * D2_ + t;
            qst_out[o] = qv;
            q_ws[o] = qv;
            float d = qv - zsh[r][t];
            lossAcc += d * d;
        }
        __syncthreads();
    }
    lsum[t] = lossAcc;
    __syncthreads();
    for (int off = 128; off > 0; off >>= 1) {
        if (t < off) lsum[t] += lsum[t + off];
        __syncthreads();
    }
    if (t == 0) atomicAdd(acc, (double)lsum[0]);
}

__global__ void finalize_loss(const double* __restrict__ acc, float* __restrict__ out0)
{
    out0[0] = (float)(1.25 * (*acc) / (double)((size_t)B_ * D2_));
}

// ---------------------------------------------------------------------------
extern "C" void kernel_launch(void* const* d_in, const int* in_sizes, int n_in,
                              void* d_out, int out_size, void* d_ws, size_t ws_size,
                              hipStream_t stream)
{
    const float* inputs = (const float*)d_in[0];
    const float* enc_w  = (const float*)d_in[1];
    const float* enc_b  = (const float*)d_in[2];
    const float* w1     = (const float*)d_in[3];
    const float* b1     = (const float*)d_in[4];
    const float* w2     = (const float*)d_in[5];
    const float* b2     = (const float*)d_in[6];
    const float* cb     = (const float*)d_in[7];
    const float* dw1    = (const float*)d_in[8];
    const float* db1    = (const float*)d_in[9];
    const float* dw2    = (const float*)d_in[10];
    const float* db2    = (const float*)d_in[11];
    const float* dec_w  = (const float*)d_in[12];
    const float* dec_b  = (const float*)d_in[13];

    float* out = (float*)d_out;
    float* x_recon = out + 1;
    float* qst     = out + 1 + (size_t)B_ * C_ * G_;

    const size_t MB = 1u << 20;
    const size_t NEED = 172 * MB;
    dim3 blk(256);

    if (ws_size >= NEED) {
        char* W = (char*)d_ws;
        unsigned short* ewt_hi = (unsigned short*)(W + 0);         // 8MB
        unsigned short* ewt_lo = (unsigned short*)(W + 8 * MB);    // 8MB
        unsigned short* h_hi   = (unsigned short*)(W + 16 * MB);   // 32MB
        unsigned short* h_lo   = (unsigned short*)(W + 48 * MB);   // 32MB
        unsigned short* w1t_hi = (unsigned short*)(W + 80 * MB);   // 2MB
        unsigned short* w1t_lo = (unsigned short*)(W + 82 * MB);   // 2MB
        unsigned short* dw2t   = (unsigned short*)(W + 84 * MB);   // 2MB (bf16 only)
        unsigned short* dwt    = (unsigned short*)(W + 86 * MB);   // 7.65MB (bf16 only)
        float* partials = (float*)(W + 94 * MB);                   // 32MB (8 slices)
        float* z1 = (float*)(W + 126 * MB);                        // 4MB
        float* z  = (float*)(W + 130 * MB);                        // 2MB
        float* q  = (float*)(W + 132 * MB);                        // 2MB
        unsigned short* r1_bf = (unsigned short*)(W + 134 * MB);   // 2MB
        unsigned short* r_bf  = (unsigned short*)(W + 136 * MB);   // 32MB -> ends 168MB
        double* csq  = (double*)(W + 168 * MB);                    // 4KB
        double* acc  = (double*)(W + 168 * MB + 4096);
        float*  csqf = (float*)(W + 168 * MB + 4096 + 64);

        // weight prep (inputs are split on the fly in K1)
        transpose_split<<<dim3(16, 32, 8), blk, 0, stream>>>(
            enc_w, (long long)G_ * D0_, ewt_hi, ewt_lo, (long long)D0_ * KP_, G_, KP_, D0_);
        transpose_split<<<dim3(8, 128, 1), blk, 0, stream>>>(
            w1, 0, w1t_hi, w1t_lo, 0, CD_, CD_, D1_);
        transpose_split<<<dim3(128, 8, 1), blk, 0, stream>>>(
            dw2, 0, dw2t, nullptr, 0, D1_, D1_, CD_);
        transpose_split<<<dim3(31, 16, 8), blk, 0, stream>>>(
            dec_w, (long long)D0_ * G_, dwt, nullptr, (long long)G_ * D0_, D0_, D0_, G_);

        // K1: h = tanh(inputs @ enc_w + enc_b); A = raw fp32, split on the fly
        mfma_split<1, 1, 1><<<dim3(4, 32, 8), blk, 0, stream>>>(
            nullptr, nullptr, inputs, C_ * G_, G_,
            ewt_hi, ewt_lo, KP_, D0_ * KP_,
            enc_b, D0_,
            nullptr, h_hi, h_lo, CD_, 512LL,
            D0_, KP_, G_, 0);

        // K2: partials[z] = h @ w1 (split-K = 8)
        mfma_split<0, 0, 0><<<dim3(2, 32, 8), blk, 0, stream>>>(
            h_hi, h_lo, nullptr, CD_, 0,
            w1t_hi, w1t_lo, CD_, 0,
            nullptr, 0,
            partials, nullptr, nullptr, D1_, (long long)B_ * D1_,
            D1_, CD_ / 8, CD_ / 8, 1);
        combine8_tanh<<<dim3(B_ * D1_ / 1024), blk, 0, stream>>>(partials, b1, z1);

        // K3: z = tanh(z1 @ w2 + b2)  (fp32)
        gemm_bt<<<dim3(2, 64, 1), blk, 0, stream>>>(
            z1, D1_, 0, w2, 0, b2, 0, z, D2_, 0, B_, D2_, D1_, 1, nullptr);

        // VQ
        vq_prep<<<dim3(1), dim3(K_), 0, stream>>>(cb, csq, csqf, acc);
        vq_kernel<<<dim3(B_ / 8), blk, 0, stream>>>(z, cb, csq, csqf, qst, q, acc);

        // K5: r1 = tanh(q @ dw1 + db1)  (fp32 compute, bf16 out)
        gemm_bt<<<dim3(4, 64, 1), blk, 0, stream>>>(
            q, D2_, 0, dw1, 0, db1, 0, nullptr, D1_, 0, B_, D1_, D2_, 1, r1_bf);

        // K6: r = tanh(r1 @ dw2 + db2), pure bf16
        mfma_bf<1, 1><<<dim3(32, 32, 1), blk, 0, stream>>>(
            r1_bf, D1_, 0,
            dw2t, D1_, 0,
            db2, 0,
            nullptr, r_bf, CD_, 0LL,
            CD_, D1_);

        // K7: x_recon = r @ dec_w + dec_b (grouped, pure bf16, fp32 out)
        mfma_bf<0, 0><<<dim3(8, 32, 8), blk, 0, stream>>>(
            r_bf, CD_, 512,
            dwt, D0_, (long long)G_ * D0_,
            dec_b, G_,
            x_recon, nullptr, C_ * G_, (long long)G_,
            G_, D0_);

        finalize_loss<<<dim3(1), dim3(1), 0, stream>>>(acc, out);
    } else {
        // -------- fallback: fp32 path --------
        float*  h   = (float*)d_ws;
        float*  z1  = h  + (size_t)B_ * CD_;
        float*  z   = z1 + (size_t)B_ * D1_;
        float*  q   = z  + (size_t)B_ * D2_;
        double* csq = (double*)(q + (size_t)B_ * D2_);
        double* acc = csq + K_;
        float*  csqf = (float*)(acc + 8);

        gemm_bt<<<dim3(D0_ / 64, B_ / 64, C_), blk, 0, stream>>>(
            inputs, C_ * G_, G_, enc_w, G_ * D0_, enc_b, D0_,
            h, CD_, D0_, B_, D0_, G_, 1, nullptr);
        gemm_bt<<<dim3(D1_ / 64, B_ / 64, 1), blk, 0, stream>>>(
            h, CD_, 0, w1, 0, b1, 0, z1, D1_, 0, B_, D1_, CD_, 1, nullptr);
        gemm_bt<<<dim3(D2_ / 64, B_ / 64, 1), blk, 0, stream>>>(
            z1, D1_, 0, w2, 0, b2, 0, z, D2_, 0, B_, D2_, D1_, 1, nullptr);
        vq_prep<<<dim3(1), dim3(K_), 0, stream>>>(cb, csq, csqf, acc);
        vq_kernel<<<dim3(B_ / 8), blk, 0, stream>>>(z, cb, csq, csqf, qst, q, acc);
        gemm_bt<<<dim3(D1_ / 64, B_ / 64, 1), blk, 0, stream>>>(
            q, D2_, 0, dw1, 0, db1, 0, z1, D1_, 0, B_, D1_, D2_, 1, nullptr);
        gemm_bt<<<dim3(CD_ / 64, B_ / 64, 1), blk, 0, stream>>>(
            z1, D1_, 0, dw2, 0, db2, 0, h, CD_, 0, B_, CD_, D1_, 1, nullptr);
        gemm_bt<<<dim3((G_ + 63) / 64, B_ / 64, C_), blk, 0, stream>>>(
            h, CD_, D0_, dec_w, D0_ * G_, dec_b, G_,
            x_recon, C_ * G_, G_, B_, G_, D0_, 0, nullptr);
        finalize_loss<<<dim3(1), dim3(1), 0, stream>>>(acc, out);
    }
}